// Round 7
// baseline (44.277 us; speedup 1.0000x reference)
//
#include <hip/hip_runtime.h>
#include <hip/hip_bf16.h>
#include <math.h>

typedef __attribute__((ext_vector_type(4))) float f32x4;
typedef __attribute__((ext_vector_type(8))) short bf16x8;

#define NB    64
#define LQ    32
#define LDOC  256
#define HDIM  768
#define DDIM  128
#define NTOK_Q (NB * LQ)        // 2048
#define NTOK_D (NB * LDOC)      // 16384
#define NTOK   (NTOK_Q + NTOK_D) // 18432

// ws layout (bytes):
#define WS_OFF_MASK 196608      // maskT : 64*16 ushort (2KB)
#define WS_OFF_QN   212992      // Qn    : 2048*128 bf16
#define WS_OFF_DN   737280      // Dn    : 16384*128 bf16

__device__ inline short f2bf(float f) {
    unsigned u = __float_as_uint(f);
    u = (u + 0x7fffu + ((u >> 16) & 1u)) >> 16;   // RNE
    return (short)u;
}

// ---------------------------------------------------------------------------
// Projection + L2 norm v7 (prep fused): block = 32 rows x 128 cols, BK=64,
// 12 steps, 4 waves (2 row-halves x 2 col-halves, 16x64 each).
// A: global_load_lds fp32, source-swizzled. B: reg-staged from raw fp32 W
// (loads issued before compute, converted+ds_write'd after -> latency hidden).
// Block 0 additionally builds the bit-transposed doc mask in its epilogue.
__global__ __launch_bounds__(256)
void proj_norm(const float* __restrict__ Qh, const float* __restrict__ Dh,
               const float* __restrict__ W,
               short* __restrict__ Qn, short* __restrict__ Dn,
               const unsigned char* __restrict__ mraw,
               unsigned short* __restrict__ maskT) {
    const int tid  = threadIdx.x;
    const int lane = tid & 63;
    const int wave = tid >> 6;
    const int g    = lane >> 4;
    const int lc   = lane & 15;
    const int wr   = wave >> 1;          // 16-row half
    const int wc   = wave & 1;           // 64-col half
    const int row0 = blockIdx.x * 32;

    const float* Asrc = (row0 < NTOK_Q) ? Qh + (size_t)row0 * HDIM
                                        : Dh + (size_t)(row0 - NTOK_Q) * HDIM;

    __shared__ alignas(16) float As[2][2048];   // [buf][row*64 + unit*4], 8KB each
    __shared__ alignas(16) short Bs[2][8192];   // [buf][n*64 + unit*8],  16KB each
    __shared__ float norms[2][2][16];

    // A: 32 rows x 16 16B-units = 512 slots; DMA direct to LDS, source-swizzled
    auto STAGE_A = [&](int buf, int t) {
#pragma unroll
        for (int i = 0; i < 2; ++i) {
            const int sb = i * 256 + wave * 64;  // wave-uniform 16B-slot base
            const int s  = sb + lane;
            const int row = s >> 4;
            const int cu  = (s & 15) ^ (row & 15);       // inverse swizzle on source
            const float* ga = Asrc + (size_t)row * HDIM + t * 64 + cu * 4;
            __builtin_amdgcn_global_load_lds(
                (const __attribute__((address_space(1))) unsigned*)ga,
                (__attribute__((address_space(3))) unsigned*)((char*)&As[buf][0] + (size_t)sb * 16),
                16, 0, 0);
        }
    };

    // B: 128 n x 8 logical 16B-units = 1024 slots; 4 slots/thread.
    float4 bl[4][2];
    auto BLOAD = [&](int t) {
#pragma unroll
        for (int i = 0; i < 4; ++i) {
            const int s = i * 256 + tid;
            const int n = s >> 3, u = s & 7;
            const float* gw = W + (size_t)n * HDIM + t * 64 + u * 8;
            bl[i][0] = *(const float4*)(gw);
            bl[i][1] = *(const float4*)(gw + 4);
        }
    };
    auto BWRITE = [&](int buf) {
#pragma unroll
        for (int i = 0; i < 4; ++i) {
            const int s = i * 256 + tid;
            const int n = s >> 3, u = s & 7;
            bf16x8 v;
            v[0] = f2bf(bl[i][0].x); v[1] = f2bf(bl[i][0].y);
            v[2] = f2bf(bl[i][0].z); v[3] = f2bf(bl[i][0].w);
            v[4] = f2bf(bl[i][1].x); v[5] = f2bf(bl[i][1].y);
            v[6] = f2bf(bl[i][1].z); v[7] = f2bf(bl[i][1].w);
            *(bf16x8*)(&Bs[buf][(size_t)n * 64 + (size_t)(u ^ (n & 7)) * 8]) = v;
        }
    };

    f32x4 acc[4];
#pragma unroll
    for (int nt = 0; nt < 4; ++nt) acc[nt] = (f32x4){0.f, 0.f, 0.f, 0.f};

    // prologue: stage tile 0 fully
    STAGE_A(0, 0);
    BLOAD(0);
    BWRITE(0);
    __syncthreads();

    for (int t = 0; t < 12; ++t) {
        const int cur = t & 1;
        if (t < 11) {                       // issue next tile's loads early
            STAGE_A(cur ^ 1, t + 1);
            BLOAD(t + 1);
        }
        __builtin_amdgcn_sched_barrier(0);  // pin load issue above compute

        const float* Ab = &As[cur][0];
        const short* Bb = &Bs[cur][0];
#pragma unroll
        for (int ks = 0; ks < 2; ++ks) {
            bf16x8 bfr[4];
#pragma unroll
            for (int nt = 0; nt < 4; ++nt) {
                const int nl = wc * 64 + nt * 16 + lc;
                const int c8 = (ks * 4 + g) ^ (nl & 7);    // read-side swizzle
                bfr[nt] = *(const bf16x8*)(Bb + (size_t)nl * 64 + c8 * 8);
            }
            const int rl = wr * 16 + lc;                   // rl & 15 == lc
            const int u0 = (ks * 8 + g * 2) ^ lc;          // read-side swizzle
            const int u1 = (ks * 8 + g * 2 + 1) ^ lc;
            const float4 a0 = *(const float4*)(Ab + (size_t)rl * 64 + u0 * 4);
            const float4 a1 = *(const float4*)(Ab + (size_t)rl * 64 + u1 * 4);
            bf16x8 af;
            af[0] = f2bf(a0.x); af[1] = f2bf(a0.y); af[2] = f2bf(a0.z); af[3] = f2bf(a0.w);
            af[4] = f2bf(a1.x); af[5] = f2bf(a1.y); af[6] = f2bf(a1.z); af[7] = f2bf(a1.w);
#pragma unroll
            for (int nt = 0; nt < 4; ++nt)
                acc[nt] = __builtin_amdgcn_mfma_f32_16x16x32_bf16(af, bfr[nt], acc[nt], 0, 0, 0);
        }
        if (t < 11) BWRITE(cur ^ 1);        // W loads had the whole compute to land
        __syncthreads();                    // drains A-DMA (vmcnt) + B writes (lgkm)
    }

    // row norms: partial over this wave's 64 cols, combine col-halves via LDS
    float part[4];
#pragma unroll
    for (int i = 0; i < 4; ++i) {
        float s = 0.f;
#pragma unroll
        for (int nt = 0; nt < 4; ++nt) s += acc[nt][i] * acc[nt][i];
        s += __shfl_xor(s, 1);
        s += __shfl_xor(s, 2);
        s += __shfl_xor(s, 4);
        s += __shfl_xor(s, 8);
        part[i] = s;
    }
    if (lc == 0) {
#pragma unroll
        for (int i = 0; i < 4; ++i) norms[wr][wc][g * 4 + i] = part[i];
    }
    __syncthreads();

    short* Obase = (row0 < NTOK_Q) ? Qn + (size_t)row0 * DDIM
                                   : Dn + (size_t)(row0 - NTOK_Q) * DDIM;
#pragma unroll
    for (int i = 0; i < 4; ++i) {
        const int rloc = g * 4 + i;                     // within 16-row tile
        const float tot = norms[wr][0][rloc] + norms[wr][1][rloc];
        const float inv = 1.f / fmaxf(sqrtf(tot), 1e-12f);
        short* dst = Obase + (size_t)(wr * 16 + rloc) * DDIM + wc * 64;
#pragma unroll
        for (int nt = 0; nt < 4; ++nt)
            dst[nt * 16 + lc] = f2bf(acc[nt][i] * inv);
    }

    // ---- block 0 epilogue: build bit-transposed doc mask (runs in parallel
    // with other blocks' GEMM; ordered before maxsim by the stream) ----
    if (blockIdx.x == 0) {
        __shared__ int dword_ok_s;
        if (tid == 0) dword_ok_s = 1;
        __syncthreads();
        const unsigned* dw = (const unsigned*)mraw;
        int ok = 1;
        for (int i = tid; i < 4096; i += 256) {   // first 16KB: safe both layouts
            unsigned v = dw[i];
            if (!(v == 0u || v == 1u || v == 0x3F800000u)) ok = 0;
        }
        if (!ok) atomicAnd(&dword_ok_s, 0);
        __syncthreads();
        const int isdw = dword_ok_s;
        for (int w = tid; w < 1024; w += 256) {   // word w: c=w>>4, lane-col=w&15
            const int c = w >> 4, lcc = w & 15;
            unsigned bits = 0;
            if (isdw) {
                for (int nt = 0; nt < 16; ++nt)
                    bits |= (dw[c * 256 + nt * 16 + lcc] ? 1u : 0u) << nt;
            } else {
                for (int nt = 0; nt < 16; ++nt)
                    bits |= (mraw[c * 256 + nt * 16 + lcc] ? 1u : 0u) << nt;
            }
            maskT[w] = (unsigned short)bits;
        }
    }
}

// ---------------------------------------------------------------------------
// MaxSim v4 (unchanged): block = (c, 8 b's), 8 waves; wave <-> one b.
// D[c] staged in 4 chunks of 64 rows, double-buffered (32KB LDS), XOR-swizzled.
__global__ __launch_bounds__(512)
void maxsim(const short* __restrict__ Qn, const short* __restrict__ Dn,
            const unsigned short* __restrict__ maskT, float* __restrict__ out) {
    const int x  = blockIdx.x & 7;            // XCD (perf heuristic only)
    const int m8 = (blockIdx.x >> 3) & 7;
    const int bg = blockIdx.x >> 6;           // b-group (8 b's)
    const int c  = x * 8 + m8;                // all 8 bg's of a c on one XCD

    const int wave = threadIdx.x >> 6;        // 0..7  <-> local b
    const int lane = threadIdx.x & 63;
    const int g = lane >> 4, lc = lane & 15;

    __shared__ alignas(16) short Ds[2][4096 * 2];   // [buf][64 rows * 128], 16KB each

    const short* dsrc = Dn + (size_t)c * LDOC * DDIM;

    auto STAGE = [&](int buf, int ch) {
#pragma unroll
        for (int i = 0; i < 2; ++i) {
            const int sb = wave * 128 + i * 64;  // wave-uniform 16B-slot base
            const int s  = sb + lane;
            const int rowl = s >> 4;             // 0..63
            const int c16  = (s & 15) ^ (rowl & 15);
            const short* ga = dsrc + (size_t)(ch * 64 + rowl) * DDIM + c16 * 8;
            __builtin_amdgcn_global_load_lds(
                (const __attribute__((address_space(1))) unsigned*)ga,
                (__attribute__((address_space(3))) unsigned*)((char*)&Ds[buf][0] + (size_t)sb * 16),
                16, 0, 0);
        }
    };

    STAGE(0, 0);

    // Q fragments: this wave's 32 q-rows (one b), full K=128
    bf16x8 qf[2][4];
    const int qrow0 = bg * 256 + wave * 32;
#pragma unroll
    for (int m = 0; m < 2; ++m) {
        const short* qb = Qn + (size_t)(qrow0 + m * 16 + lc) * DDIM;
#pragma unroll
        for (int ks = 0; ks < 4; ++ks)
            qf[m][ks] = *(const bf16x8*)(qb + ks * 32 + g * 8);
    }
    const unsigned mbits = maskT[c * 16 + lc];    // bit nt = mask[c][nt*16+lc]

    __syncthreads();   // chunk 0 landed

    float rmax[2][4];
#pragma unroll
    for (int m = 0; m < 2; ++m)
#pragma unroll
        for (int i = 0; i < 4; ++i) rmax[m][i] = -INFINITY;

    for (int ch = 0; ch < 4; ++ch) {
        const int buf = ch & 1;
        if (ch < 3) STAGE(buf ^ 1, ch + 1);       // fly under this chunk's compute
        const short* Db = &Ds[buf][0];
#pragma unroll
        for (int j = 0; j < 4; ++j) {
            const int rowl = j * 16 + lc;
            bf16x8 bf[4];
#pragma unroll
            for (int ks = 0; ks < 4; ++ks) {
                const int c16 = (ks * 4 + g) ^ lc;     // read-side swizzle
                bf[ks] = *(const bf16x8*)(Db + (size_t)rowl * DDIM + c16 * 8);
            }
            const bool on = (mbits >> (ch * 4 + j)) & 1;
#pragma unroll
            for (int m = 0; m < 2; ++m) {
                f32x4 acc = (f32x4){0.f, 0.f, 0.f, 0.f};
#pragma unroll
                for (int ks = 0; ks < 4; ++ks)
                    acc = __builtin_amdgcn_mfma_f32_16x16x32_bf16(qf[m][ks], bf[ks], acc, 0, 0, 0);
#pragma unroll
                for (int i = 0; i < 4; ++i)
                    rmax[m][i] = on ? fmaxf(rmax[m][i], acc[i]) : rmax[m][i];
            }
        }
        __syncthreads();   // next chunk landed; this chunk's reads done block-wide
    }

    // cross-col max (16 lc lanes), then sum this wave's 32 rows
    float s = 0.f;
#pragma unroll
    for (int m = 0; m < 2; ++m)
#pragma unroll
        for (int i = 0; i < 4; ++i) {
            float r = rmax[m][i];
            r = fmaxf(r, __shfl_xor(r, 1));
            r = fmaxf(r, __shfl_xor(r, 2));
            r = fmaxf(r, __shfl_xor(r, 4));
            r = fmaxf(r, __shfl_xor(r, 8));
            s += r;
        }
    s += __shfl_xor(s, 16);
    s += __shfl_xor(s, 32);

    if (lane == 0) {
        const int b = bg * 8 + wave;
        out[(size_t)b * NB + c] = s;
    }
}

// ---------------------------------------------------------------------------
extern "C" void kernel_launch(void* const* d_in, const int* in_sizes, int n_in,
                              void* d_out, int out_size, void* d_ws, size_t ws_size,
                              hipStream_t stream) {
    const float* Qh = (const float*)d_in[0];
    const float* Dh = (const float*)d_in[1];
    const float* W  = (const float*)d_in[2];
    const unsigned char* dm = (const unsigned char*)d_in[3];
    float* out = (float*)d_out;
    char* ws = (char*)d_ws;

    unsigned short* maskT = (unsigned short*)(ws + WS_OFF_MASK);
    short*          Qn    = (short*)(ws + WS_OFF_QN);
    short*          Dn    = (short*)(ws + WS_OFF_DN);

    proj_norm<<<NTOK / 32, 256, 0, stream>>>(Qh, Dh, W, Qn, Dn, dm, maskT);
    maxsim<<<512, 512, 0, stream>>>(Qn, Dn, maskT, out);
}